// Round 26
// baseline (75.417 us; speedup 1.0000x reference)
//
#include <hip/hip_runtime.h>

#define NWIN 4096
#define DIM 96
#define HEADS 6
#define NTOK 64
#define QS 0.36067376022224085f  // 0.25 * log2(e): folded into q-weights/bias

typedef __bf16 bf16x8 __attribute__((ext_vector_type(8)));
typedef __bf16 bf16x4 __attribute__((ext_vector_type(4)));
typedef short  s16x4  __attribute__((ext_vector_type(4)));
typedef float  f32x4  __attribute__((ext_vector_type(4)));

#if __has_builtin(__builtin_amdgcn_exp2f)
#define EXP2(x) __builtin_amdgcn_exp2f(x)   // bare v_exp_f32, no libm wrapper
#else
#define EXP2(x) exp2f(x)
#endif
#if __has_builtin(__builtin_amdgcn_rcpf)
#define RCP(x) __builtin_amdgcn_rcpf(x)     // bare v_rcp_f32 (2^-22 rel err)
#else
#define RCP(x) (1.0f / (x))
#endif

// d_ws layout
#define WS_QKVW 0                   // 288*96 bf16 = 55296 B (q rows prescaled)
#define WS_PROJW 55296              // 96*96 bf16  = 18432 B
#define WS_BIAS 73728               // 6*16*64 float4 = 98304 B (x log2e)
#define WS_TOTAL 172032

__device__ __forceinline__ f32x4 mfma32(bf16x8 a, bf16x8 b, f32x4 c) {
  return __builtin_amdgcn_mfma_f32_16x16x32_bf16(a, b, c, 0, 0, 0);
}
// K=16 MFMA. Fragment alignment facts (verified r7-r25):
//  * A/B fragment lane(l16,lq) holds row/col=l16, k=4*lq+e  — identical to
//    the W*X^T D-fragment (row=4lq+r, col=l16), so K,Q stay in registers.
//  * QK^T output s[a] = S[q=l16][kv=16a+4lq+r] — IS the PV A-frag chunk a.
//  * V-phase D-frag for mt=a IS the PV B-frag chunk a.
//  * rowsum via mfma16k(pa[a], ones) lands in the SAME D-layout as the PV
//    output -> rv[r] normalizes exactly the row oacc[r] holds (r22-proven).
__device__ __forceinline__ f32x4 mfma16k(bf16x4 a, bf16x4 b, f32x4 c) {
  return __builtin_amdgcn_mfma_f32_16x16x16bf16_1k(
      __builtin_bit_cast(s16x4, a), __builtin_bit_cast(s16x4, b), c, 0, 0, 0);
}

__device__ __forceinline__ bf16x8 cvt8(const float* p) {
  const float4* q = (const float4*)p;
  float4 a = q[0];
  float4 b = q[1];
  bf16x8 r;
  r[0] = (__bf16)a.x; r[1] = (__bf16)a.y; r[2] = (__bf16)a.z; r[3] = (__bf16)a.w;
  r[4] = (__bf16)b.x; r[5] = (__bf16)b.y; r[6] = (__bf16)b.z; r[7] = (__bf16)b.w;
  return r;
}

// Pre-pass: weights -> bf16 (q rows x QS so QK logits arrive pre-scaled for
// exp2); bias gathered into MFMA-fragment order and x log2(e):
// bias[((h*16 + bq*4 + a)*64 + lane)*4 + r] = log2e * rpb[rpi[qrow*64+kcol]*6+h]
// (Replay-stable staging across r2/4/6/8/9/14/15/16/19-25.)
__global__ void prep_kernel(const float* __restrict__ qkv_w,
                            const float* __restrict__ proj_w,
                            const float* __restrict__ rpb,
                            const int* __restrict__ rpi,
                            char* __restrict__ ws) {
  int i = blockIdx.x * blockDim.x + threadIdx.x;
  __bf16* qw = (__bf16*)(ws + WS_QKVW);
  __bf16* pw = (__bf16*)(ws + WS_PROJW);
  float* bias = (float*)(ws + WS_BIAS);
  if (i < 288 * 96) {
    float v = qkv_w[i];
    if (i < 96 * 96) v *= QS;  // q feature rows: fold 0.25*log2e
    qw[i] = (__bf16)v;
  }
  int j = i - 288 * 96;
  if (j >= 0 && j < 96 * 96) pw[j] = (__bf16)proj_w[j];
  int t = i - (288 * 96 + 96 * 96);
  if (t >= 0 && t < HEADS * 16 * 64 * 4) {
    int r = t & 3;
    int lane = (t >> 2) & 63;
    int ba = (t >> 8) & 15;
    int h = t >> 12;
    int bq = ba >> 2, a = ba & 3;
    int l16 = lane & 15, lq = lane >> 4;
    int qrow = 16 * bq + l16;
    int kcol = 16 * a + 4 * lq + r;
    bias[t] = 1.4426950408889634f * rpb[rpi[qrow * 64 + kcol] * HEADS + h];
  }
}

// r26: r23/r25 (71.4us optimum) + FUSED K/Q/V phases. The three phases read
// the identical 12 XV fragments; fusing reads each once (36 -> 12
// ds_read_b128/head, -67% LDS pipe), issues all 9 weight loads together
// (1 exposed L2 batch vs 3 serialized), and runs 3 independent MFMA chains
// per mt (better ILP). Register cost ~+35 (76 -> ~110, cap 128 at
// launch_bounds(128,4)); FETCH/WRITE are the spill tripwire — if the VGPR
// cost eats the gain (r24 pattern), revert to r25.
template <bool USE_WS>
__global__ __launch_bounds__(128, 4) void win_attn(
    const float* __restrict__ x,
    const int* __restrict__ rpi,
    const float* __restrict__ qkv_w,
    const float* __restrict__ qkv_b,
    const float* __restrict__ proj_w,
    const float* __restrict__ proj_b,
    const float* __restrict__ rpb,
    const char* __restrict__ ws,
    float* __restrict__ out) {
  __shared__ __align__(16) __bf16 xfrag[6144];   // 12 frags * 512 bf16
  __shared__ __align__(16) __bf16 ao[64 * 104];  // 13312 B

  const int tid = (int)threadIdx.x;
  const int wv = tid >> 6;  // 0..1
  const int lane = tid & 63;
  const int l16 = lane & 15;
  const int lq = lane >> 4;
  const int b = (int)blockIdx.x;

  const float* xw = x + (size_t)b * (NTOK * DIM);
  const __bf16* qwb = (const __bf16*)(ws + WS_QKVW);
  const __bf16* pwb = (const __bf16*)(ws + WS_PROJW);

  bf16x4 ones4;
#pragma unroll
  for (int r = 0; r < 4; ++r) ones4[r] = (__bf16)1.0f;

  // ---- stage x fragments (wave wv does frags 6wv..6wv+5; mt,ks static) ----
#pragma unroll
  for (int ff = 0; ff < 6; ++ff) {
    const int mt = 2 * wv + ff / 3;
    const int ks = ff % 3;
    const int f = 6 * wv + ff;
    bf16x8 v = cvt8(xw + (16 * mt + l16) * DIM + 32 * ks + 8 * lq);
    *(bf16x8*)(xfrag + (f * 64 + lane) * 8) = v;
  }
  __syncthreads();

#define XV(mt, ks) (*(const bf16x8*)(xfrag + (((mt) * 3 + (ks)) * 64 + lane) * 8))

  // ---- 3 heads sequentially per wave; NO unroll (register discipline) ----
#pragma unroll 1
  for (int hh = 0; hh < 3; ++hh) {
    const int h = wv + 2 * hh;

    // ---- fused K/Q/V: all 9 weight loads issue together; XV read ONCE ----
    bf16x8 wbq[3], wbk[3], wbv[3];
    {
      const int qrow = h * 16, krow = (HEADS + h) * 16,
                vrow = (2 * HEADS + h) * 16;
#pragma unroll
      for (int ks = 0; ks < 3; ++ks) {
        if constexpr (USE_WS) {
          wbq[ks] = *(const bf16x8*)(qwb + (qrow + l16) * 96 + 32 * ks + 8 * lq);
          wbk[ks] = *(const bf16x8*)(qwb + (krow + l16) * 96 + 32 * ks + 8 * lq);
          wbv[ks] = *(const bf16x8*)(qwb + (vrow + l16) * 96 + 32 * ks + 8 * lq);
        } else {
          wbq[ks] = cvt8(qkv_w + (qrow + l16) * 96 + 32 * ks + 8 * lq);
          wbk[ks] = cvt8(qkv_w + (krow + l16) * 96 + 32 * ks + 8 * lq);
          wbv[ks] = cvt8(qkv_w + (vrow + l16) * 96 + 32 * ks + 8 * lq);
        }
      }
    }
    const float4 qb4 = *(const float4*)(qkv_b + h * 16 + 4 * lq);
    const float4 kb4 = *(const float4*)(qkv_b + (HEADS + h) * 16 + 4 * lq);
    const float vbb = qkv_b[(2 * HEADS + h) * 16 + l16];

    bf16x4 kb[4], qv4[4], vb4[4];
#pragma unroll
    for (int mt = 0; mt < 4; ++mt) {
      f32x4 kacc = {kb4.x, kb4.y, kb4.z, kb4.w};
      f32x4 qacc;
      if constexpr (USE_WS) {
        qacc[0] = qb4.x * QS; qacc[1] = qb4.y * QS;
        qacc[2] = qb4.z * QS; qacc[3] = qb4.w * QS;
      } else {
        qacc[0] = qb4.x; qacc[1] = qb4.y; qacc[2] = qb4.z; qacc[3] = qb4.w;
      }
      f32x4 vacc = {vbb, vbb, vbb, vbb};
#pragma unroll
      for (int ks = 0; ks < 3; ++ks) {
        const bf16x8 xv = XV(mt, ks);          // single LDS read, 3 uses
        kacc = mfma32(wbk[ks], xv, kacc);      // K: W * X^T
        qacc = mfma32(wbq[ks], xv, qacc);      // Q: W * X^T (prescaled)
        vacc = mfma32(xv, wbv[ks], vacc);      // V: X * W^T
      }
#pragma unroll
      for (int r = 0; r < 4; ++r) {
        kb[mt][r] = (__bf16)kacc[r];
        if constexpr (USE_WS)
          qv4[mt][r] = (__bf16)qacc[r];
        else
          qv4[mt][r] = (__bf16)(qacc[r] * QS);
        vb4[mt][r] = (__bf16)vacc[r];
      }
    }

    // attention per q-tile: pure register dataflow; bias double-buffered
    const float4* bias4 = (const float4*)(ws + WS_BIAS) + (h << 10);
    f32x4 bc[4];  // current tile's bias (C-init)
    if constexpr (USE_WS) {
#pragma unroll
      for (int a = 0; a < 4; ++a)
        bc[a] = __builtin_bit_cast(f32x4, bias4[a * 64 + lane]);
    }

#pragma unroll
    for (int bq = 0; bq < 4; ++bq) {
      f32x4 s[4];
      if constexpr (USE_WS) {
#pragma unroll
        for (int a = 0; a < 4; ++a) s[a] = bc[a];
        // prefetch bq+1's bias: issues before softmax/PV, lands by next QK
        if (bq < 3) {
#pragma unroll
          for (int a = 0; a < 4; ++a)
            bc[a] = __builtin_bit_cast(f32x4,
                                       bias4[((bq + 1) * 4 + a) * 64 + lane]);
        }
      } else {
#pragma unroll
        for (int a = 0; a < 4; ++a)
#pragma unroll
          for (int r = 0; r < 4; ++r)
            s[a][r] = 1.4426950408889634f *
                      rpb[rpi[(16 * bq + l16) * 64 + 16 * a + 4 * lq + r] *
                              HEADS + h];
      }

      // QK^T: S^T = K * Q^T with (log2e-scaled) bias as C-init
#pragma unroll
      for (int a = 0; a < 4; ++a) s[a] = mfma16k(kb[a], qv4[bq], s[a]);

      // P = exp2(S) in bf16 (logits pre-scaled by log2e -> bare v_exp_f32)
      bf16x4 pa[4];
#pragma unroll
      for (int a = 0; a < 4; ++a)
#pragma unroll
        for (int r = 0; r < 4; ++r) pa[a][r] = (__bf16)EXP2(s[a][r]);

      // PV and rowsum together on the MFMA pipe; identical D-layouts
      f32x4 oacc = {0.f, 0.f, 0.f, 0.f};
      f32x4 tsum4 = {0.f, 0.f, 0.f, 0.f};
#pragma unroll
      for (int a = 0; a < 4; ++a) {
        oacc = mfma16k(pa[a], vb4[a], oacc);
        tsum4 = mfma16k(pa[a], ones4, tsum4);
      }

#pragma unroll
      for (int r = 0; r < 4; ++r)
        ao[(16 * bq + 4 * lq + r) * 104 + 16 * h + l16] =
            (__bf16)(oacc[r] * RCP(tsum4[r]));
    }
  }
#undef XV
  __syncthreads();  // ao complete (xfrag disjoint: no overlay hazard)

  // ---- proj: 3 column-tiles per wave (c = wv, wv+2, wv+4); no hoisting ----
  float* outw = out + (size_t)b * (NTOK * DIM);
#pragma unroll 1
  for (int cc = 0; cc < 3; ++cc) {
    const int c = wv + 2 * cc;
    bf16x8 wpb[3];
#pragma unroll
    for (int ks = 0; ks < 3; ++ks) {
      if constexpr (USE_WS)
        wpb[ks] = *(const bf16x8*)(pwb + (16 * c + l16) * 96 + 32 * ks + 8 * lq);
      else
        wpb[ks] = cvt8(proj_w + (16 * c + l16) * 96 + 32 * ks + 8 * lq);
    }
    const float pb2 = proj_b[16 * c + l16];
#pragma unroll
    for (int mt = 0; mt < 4; ++mt) {
      f32x4 acc = {pb2, pb2, pb2, pb2};  // bias C-init (per-col broadcast)
#pragma unroll
      for (int ks = 0; ks < 3; ++ks) {
        bf16x8 aa =
            *(const bf16x8*)(ao + (16 * mt + l16) * 104 + 32 * ks + 8 * lq);
        acc = mfma32(aa, wpb[ks], acc);
      }
#pragma unroll
      for (int r = 0; r < 4; ++r)
        outw[(16 * mt + 4 * lq + r) * 96 + 16 * c + l16] = acc[r];
    }
  }
}

extern "C" void kernel_launch(void* const* d_in, const int* in_sizes, int n_in,
                              void* d_out, int out_size, void* d_ws, size_t ws_size,
                              hipStream_t stream) {
  const float* x      = (const float*)d_in[0];
  const int*   rpi    = (const int*)d_in[1];
  const float* qkv_w  = (const float*)d_in[2];
  const float* qkv_b  = (const float*)d_in[3];
  const float* proj_w = (const float*)d_in[4];
  const float* proj_b = (const float*)d_in[5];
  const float* rpb    = (const float*)d_in[6];
  float* out = (float*)d_out;

  if (ws_size >= (size_t)WS_TOTAL) {
    prep_kernel<<<240, 256, 0, stream>>>(qkv_w, proj_w, rpb, rpi, (char*)d_ws);
    win_attn<true><<<NWIN, 128, 0, stream>>>(x, rpi, qkv_w, qkv_b, proj_w,
                                             proj_b, rpb, (const char*)d_ws,
                                             out);
  } else {
    win_attn<false><<<NWIN, 128, 0, stream>>>(x, rpi, qkv_w, qkv_b, proj_w,
                                              proj_b, rpb, (const char*)d_ws,
                                              out);
  }
}

// Round 27
// 70.991 us; speedup vs baseline: 1.0624x; 1.0624x over previous
//
#include <hip/hip_runtime.h>

#define NWIN 4096
#define DIM 96
#define HEADS 6
#define NTOK 64
#define QS 0.36067376022224085f  // 0.25 * log2(e): folded into q-weights/bias

typedef __bf16 bf16x8 __attribute__((ext_vector_type(8)));
typedef __bf16 bf16x4 __attribute__((ext_vector_type(4)));
typedef short  s16x4  __attribute__((ext_vector_type(4)));
typedef float  f32x4  __attribute__((ext_vector_type(4)));

#if __has_builtin(__builtin_amdgcn_exp2f)
#define EXP2(x) __builtin_amdgcn_exp2f(x)   // bare v_exp_f32, no libm wrapper
#else
#define EXP2(x) exp2f(x)
#endif
#if __has_builtin(__builtin_amdgcn_rcpf)
#define RCP(x) __builtin_amdgcn_rcpf(x)     // bare v_rcp_f32 (2^-22 rel err)
#else
#define RCP(x) (1.0f / (x))
#endif

// d_ws layout
#define WS_QKVW 0                   // 288*96 bf16 = 55296 B (q rows prescaled)
#define WS_PROJW 55296              // 96*96 bf16  = 18432 B
#define WS_BIAS 73728               // 6*16*64 float4 = 98304 B (x log2e)
#define WS_TOTAL 172032

__device__ __forceinline__ f32x4 mfma32(bf16x8 a, bf16x8 b, f32x4 c) {
  return __builtin_amdgcn_mfma_f32_16x16x32_bf16(a, b, c, 0, 0, 0);
}
// K=16 MFMA. Fragment alignment facts (verified r7-r26):
//  * A/B fragment lane(l16,lq) holds row/col=l16, k=4*lq+e  — identical to
//    the W*X^T D-fragment (row=4lq+r, col=l16), so K,Q stay in registers.
//  * QK^T output s[a] = S[q=l16][kv=16a+4lq+r] — IS the PV A-frag chunk a.
//  * V-phase D-frag for mt=a IS the PV B-frag chunk a.
//  * rowsum via mfma16k(pa[a], ones) lands in the SAME D-layout as the PV
//    output -> rv[r] normalizes exactly the row oacc[r] holds (r22-proven).
// FINAL (r27 = r23/r25, the measured optimum): 71.4us, VGPR 76, no spill,
// absmax 1.22e-4, replay-stable. r24 (deeper prefetch, VGPR 96) and r26
// (fused KQV phases, VGPR 88) both regressed via the occupancy tier loss —
// r23 sits on the register-vs-latency Pareto frontier. Ladder: 197 (r1) ->
// 86.6 (r4 spill-free structure) -> 82 (r8/r9 register dataflow) -> 75.9
// (r21 exp2/rcp fold) -> 73.9 (r22 mfma-ones rowsum) -> 71.4 (r23 bias
// prefetch). Not a classical roofline (MfmaUtil 17.5%, VALUBusy 33%, HBM
// 21%); binding constraint is per-window serial latency x ~9 waves/CU
// steady-state residency, robust across ten structural variants.
__device__ __forceinline__ f32x4 mfma16k(bf16x4 a, bf16x4 b, f32x4 c) {
  return __builtin_amdgcn_mfma_f32_16x16x16bf16_1k(
      __builtin_bit_cast(s16x4, a), __builtin_bit_cast(s16x4, b), c, 0, 0, 0);
}

__device__ __forceinline__ bf16x8 cvt8(const float* p) {
  const float4* q = (const float4*)p;
  float4 a = q[0];
  float4 b = q[1];
  bf16x8 r;
  r[0] = (__bf16)a.x; r[1] = (__bf16)a.y; r[2] = (__bf16)a.z; r[3] = (__bf16)a.w;
  r[4] = (__bf16)b.x; r[5] = (__bf16)b.y; r[6] = (__bf16)b.z; r[7] = (__bf16)b.w;
  return r;
}

// Pre-pass: weights -> bf16 (q rows x QS so QK logits arrive pre-scaled for
// exp2); bias gathered into MFMA-fragment order and x log2(e):
// bias[((h*16 + bq*4 + a)*64 + lane)*4 + r] = log2e * rpb[rpi[qrow*64+kcol]*6+h]
// (Replay-stable staging across r2/4/6/8/9/14/15/16/19-26.)
__global__ void prep_kernel(const float* __restrict__ qkv_w,
                            const float* __restrict__ proj_w,
                            const float* __restrict__ rpb,
                            const int* __restrict__ rpi,
                            char* __restrict__ ws) {
  int i = blockIdx.x * blockDim.x + threadIdx.x;
  __bf16* qw = (__bf16*)(ws + WS_QKVW);
  __bf16* pw = (__bf16*)(ws + WS_PROJW);
  float* bias = (float*)(ws + WS_BIAS);
  if (i < 288 * 96) {
    float v = qkv_w[i];
    if (i < 96 * 96) v *= QS;  // q feature rows: fold 0.25*log2e
    qw[i] = (__bf16)v;
  }
  int j = i - 288 * 96;
  if (j >= 0 && j < 96 * 96) pw[j] = (__bf16)proj_w[j];
  int t = i - (288 * 96 + 96 * 96);
  if (t >= 0 && t < HEADS * 16 * 64 * 4) {
    int r = t & 3;
    int lane = (t >> 2) & 63;
    int ba = (t >> 8) & 15;
    int h = t >> 12;
    int bq = ba >> 2, a = ba & 3;
    int l16 = lane & 15, lq = lane >> 4;
    int qrow = 16 * bq + l16;
    int kcol = 16 * a + 4 * lq + r;
    bias[t] = 1.4426950408889634f * rpb[rpi[qrow * 64 + kcol] * HEADS + h];
  }
}

template <bool USE_WS>
__global__ __launch_bounds__(128, 4) void win_attn(
    const float* __restrict__ x,
    const int* __restrict__ rpi,
    const float* __restrict__ qkv_w,
    const float* __restrict__ qkv_b,
    const float* __restrict__ proj_w,
    const float* __restrict__ proj_b,
    const float* __restrict__ rpb,
    const char* __restrict__ ws,
    float* __restrict__ out) {
  __shared__ __align__(16) __bf16 xfrag[6144];   // 12 frags * 512 bf16
  __shared__ __align__(16) __bf16 ao[64 * 104];  // 13312 B

  const int tid = (int)threadIdx.x;
  const int wv = tid >> 6;  // 0..1
  const int lane = tid & 63;
  const int l16 = lane & 15;
  const int lq = lane >> 4;
  const int b = (int)blockIdx.x;

  const float* xw = x + (size_t)b * (NTOK * DIM);
  const __bf16* qwb = (const __bf16*)(ws + WS_QKVW);
  const __bf16* pwb = (const __bf16*)(ws + WS_PROJW);

  bf16x4 ones4;
#pragma unroll
  for (int r = 0; r < 4; ++r) ones4[r] = (__bf16)1.0f;

  // ---- stage x fragments (wave wv does frags 6wv..6wv+5; mt,ks static) ----
#pragma unroll
  for (int ff = 0; ff < 6; ++ff) {
    const int mt = 2 * wv + ff / 3;
    const int ks = ff % 3;
    const int f = 6 * wv + ff;
    bf16x8 v = cvt8(xw + (16 * mt + l16) * DIM + 32 * ks + 8 * lq);
    *(bf16x8*)(xfrag + (f * 64 + lane) * 8) = v;
  }
  __syncthreads();

#define XV(mt, ks) (*(const bf16x8*)(xfrag + (((mt) * 3 + (ks)) * 64 + lane) * 8))

  // ---- 3 heads sequentially per wave; NO unroll (register discipline) ----
#pragma unroll 1
  for (int hh = 0; hh < 3; ++hh) {
    const int h = wv + 2 * hh;

    // K phase: D = Wk * X^T + kb (bias as C-init); D-frag stays in regs
    bf16x4 kb[4];
    {
      const int frow = (HEADS + h) * 16;
      bf16x8 wb[3];
#pragma unroll
      for (int ks = 0; ks < 3; ++ks) {
        if constexpr (USE_WS)
          wb[ks] = *(const bf16x8*)(qwb + (frow + l16) * 96 + 32 * ks + 8 * lq);
        else
          wb[ks] = cvt8(qkv_w + (frow + l16) * 96 + 32 * ks + 8 * lq);
      }
      const float4 kb4 = *(const float4*)(qkv_b + frow + 4 * lq);
#pragma unroll
      for (int mt = 0; mt < 4; ++mt) {
        f32x4 acc = {kb4.x, kb4.y, kb4.z, kb4.w};
#pragma unroll
        for (int ks = 0; ks < 3; ++ks) acc = mfma32(wb[ks], XV(mt, ks), acc);
#pragma unroll
        for (int r = 0; r < 4; ++r) kb[mt][r] = (__bf16)acc[r];
      }
    }

    // Q phase: D = Wq' * X^T + qb' (weights prescaled by QS in prep)
    bf16x4 qv4[4];
    {
      const int frow = h * 16;
      bf16x8 wb[3];
#pragma unroll
      for (int ks = 0; ks < 3; ++ks) {
        if constexpr (USE_WS)
          wb[ks] = *(const bf16x8*)(qwb + (frow + l16) * 96 + 32 * ks + 8 * lq);
        else
          wb[ks] = cvt8(qkv_w + (frow + l16) * 96 + 32 * ks + 8 * lq);
      }
      const float4 qb4 = *(const float4*)(qkv_b + frow + 4 * lq);
#pragma unroll
      for (int mt = 0; mt < 4; ++mt) {
        f32x4 acc;
        if constexpr (USE_WS) {
          acc[0] = qb4.x * QS; acc[1] = qb4.y * QS;
          acc[2] = qb4.z * QS; acc[3] = qb4.w * QS;
        } else {
          acc[0] = qb4.x; acc[1] = qb4.y; acc[2] = qb4.z; acc[3] = qb4.w;
        }
#pragma unroll
        for (int ks = 0; ks < 3; ++ks) acc = mfma32(wb[ks], XV(mt, ks), acc);
#pragma unroll
        for (int r = 0; r < 4; ++r) {
          if constexpr (USE_WS)
            qv4[mt][r] = (__bf16)acc[r];          // scale already in weights
          else
            qv4[mt][r] = (__bf16)(acc[r] * QS);   // fallback: scale here
        }
      }
    }

    // V phase: D = X * Wv^T + vb (col-bias broadcast C-init)
    bf16x4 vb4[4];
    {
      const int frow = (2 * HEADS + h) * 16;
      bf16x8 wb[3];
#pragma unroll
      for (int ks = 0; ks < 3; ++ks) {
        if constexpr (USE_WS)
          wb[ks] = *(const bf16x8*)(qwb + (frow + l16) * 96 + 32 * ks + 8 * lq);
        else
          wb[ks] = cvt8(qkv_w + (frow + l16) * 96 + 32 * ks + 8 * lq);
      }
      const float vb = qkv_b[frow + l16];
#pragma unroll
      for (int mt = 0; mt < 4; ++mt) {
        f32x4 acc = {vb, vb, vb, vb};
#pragma unroll
        for (int ks = 0; ks < 3; ++ks) acc = mfma32(XV(mt, ks), wb[ks], acc);
#pragma unroll
        for (int r = 0; r < 4; ++r) vb4[mt][r] = (__bf16)acc[r];
      }
    }

    // attention per q-tile: pure register dataflow; bias double-buffered
    const float4* bias4 = (const float4*)(ws + WS_BIAS) + (h << 10);
    f32x4 bc[4];  // current tile's bias (C-init)
    if constexpr (USE_WS) {
#pragma unroll
      for (int a = 0; a < 4; ++a)
        bc[a] = __builtin_bit_cast(f32x4, bias4[a * 64 + lane]);
    }

#pragma unroll
    for (int bq = 0; bq < 4; ++bq) {
      f32x4 s[4];
      if constexpr (USE_WS) {
#pragma unroll
        for (int a = 0; a < 4; ++a) s[a] = bc[a];
        // prefetch bq+1's bias: issues before softmax/PV, lands by next QK
        if (bq < 3) {
#pragma unroll
          for (int a = 0; a < 4; ++a)
            bc[a] = __builtin_bit_cast(f32x4,
                                       bias4[((bq + 1) * 4 + a) * 64 + lane]);
        }
      } else {
#pragma unroll
        for (int a = 0; a < 4; ++a)
#pragma unroll
          for (int r = 0; r < 4; ++r)
            s[a][r] = 1.4426950408889634f *
                      rpb[rpi[(16 * bq + l16) * 64 + 16 * a + 4 * lq + r] *
                              HEADS + h];
      }

      // QK^T: S^T = K * Q^T with (log2e-scaled) bias as C-init
#pragma unroll
      for (int a = 0; a < 4; ++a) s[a] = mfma16k(kb[a], qv4[bq], s[a]);

      // P = exp2(S) in bf16 (logits pre-scaled by log2e -> bare v_exp_f32)
      bf16x4 pa[4];
#pragma unroll
      for (int a = 0; a < 4; ++a)
#pragma unroll
        for (int r = 0; r < 4; ++r) pa[a][r] = (__bf16)EXP2(s[a][r]);

      // PV and rowsum together on the MFMA pipe; identical D-layouts
      f32x4 oacc = {0.f, 0.f, 0.f, 0.f};
      f32x4 tsum4 = {0.f, 0.f, 0.f, 0.f};
#pragma unroll
      for (int a = 0; a < 4; ++a) {
        oacc = mfma16k(pa[a], vb4[a], oacc);
        tsum4 = mfma16k(pa[a], ones4, tsum4);
      }

#pragma unroll
      for (int r = 0; r < 4; ++r)
        ao[(16 * bq + 4 * lq + r) * 104 + 16 * h + l16] =
            (__bf16)(oacc[r] * RCP(tsum4[r]));
    }
  }
#undef XV
  __syncthreads();  // ao complete (xfrag disjoint: no overlay hazard)

  // ---- proj: 3 column-tiles per wave (c = wv, wv+2, wv+4); no hoisting ----
  float* outw = out + (size_t)b * (NTOK * DIM);
#pragma unroll 1
  for (int cc = 0; cc < 3; ++cc) {
    const int c = wv + 2 * cc;
    bf16x8 wpb[3];
#pragma unroll
    for (int ks = 0; ks < 3; ++ks) {
      if constexpr (USE_WS)
        wpb[ks] = *(const bf16x8*)(pwb + (16 * c + l16) * 96 + 32 * ks + 8 * lq);
      else
        wpb[ks] = cvt8(proj_w + (16 * c + l16) * 96 + 32 * ks + 8 * lq);
    }
    const float pb2 = proj_b[16 * c + l16];
#pragma unroll
    for (int mt = 0; mt < 4; ++mt) {
      f32x4 acc = {pb2, pb2, pb2, pb2};  // bias C-init (per-col broadcast)
#pragma unroll
      for (int ks = 0; ks < 3; ++ks) {
        bf16x8 aa =
            *(const bf16x8*)(ao + (16 * mt + l16) * 104 + 32 * ks + 8 * lq);
        acc = mfma32(aa, wpb[ks], acc);
      }
#pragma unroll
      for (int r = 0; r < 4; ++r)
        outw[(16 * mt + 4 * lq + r) * 96 + 16 * c + l16] = acc[r];
    }
  }
}

extern "C" void kernel_launch(void* const* d_in, const int* in_sizes, int n_in,
                              void* d_out, int out_size, void* d_ws, size_t ws_size,
                              hipStream_t stream) {
  const float* x      = (const float*)d_in[0];
  const int*   rpi    = (const int*)d_in[1];
  const float* qkv_w  = (const float*)d_in[2];
  const float* qkv_b  = (const float*)d_in[3];
  const float* proj_w = (const float*)d_in[4];
  const float* proj_b = (const float*)d_in[5];
  const float* rpb    = (const float*)d_in[6];
  float* out = (float*)d_out;

  if (ws_size >= (size_t)WS_TOTAL) {
    prep_kernel<<<240, 256, 0, stream>>>(qkv_w, proj_w, rpb, rpi, (char*)d_ws);
    win_attn<true><<<NWIN, 128, 0, stream>>>(x, rpi, qkv_w, qkv_b, proj_w,
                                             proj_b, rpb, (const char*)d_ws,
                                             out);
  } else {
    win_attn<false><<<NWIN, 128, 0, stream>>>(x, rpi, qkv_w, qkv_b, proj_w,
                                              proj_b, rpb, (const char*)d_ws,
                                              out);
  }
}